// Round 4
// baseline (858.176 us; speedup 1.0000x reference)
//
#include <hip/hip_runtime.h>

#define B_   4
#define C_   512
#define S_   4096
#define G_   32
#define CPG_ 16
#define EPS_ 1e-6f

typedef unsigned short u16;
typedef __bf16 bf16x8 __attribute__((ext_vector_type(8)));
typedef float  f32x4  __attribute__((ext_vector_type(4)));

__device__ __forceinline__ u16 f2bf(float f) {
  unsigned u = __float_as_uint(f);
  u += 0x7fffu + ((u >> 16) & 1u);   // RNE
  return (u16)(u >> 16);
}
__device__ __forceinline__ float bf2f(u16 h) {
  return __uint_as_float((unsigned)h << 16);
}

__device__ __forceinline__ void g2lds16(const void* g, void* l) {
  __builtin_amdgcn_global_load_lds(
      (const __attribute__((address_space(1))) void*)g,
      (__attribute__((address_space(3))) void*)l, 16, 0, 0);
}

#define BAR()    __builtin_amdgcn_s_barrier()
#define SCHED0() __builtin_amdgcn_sched_barrier(0)
#define WAITV0   asm volatile("s_waitcnt vmcnt(0)" ::: "memory")

// chunked XCD swizzle (bijective when nwg % 8 == 0 — all grids here satisfy it)
__device__ __forceinline__ void xcd_swz(int& bx, int& by, int& bz) {
  const int gx = gridDim.x, gy = gridDim.y;
  const int nwg = gx * gy * (int)gridDim.z;
  const int flat = blockIdx.x + gx * (blockIdx.y + gy * blockIdx.z);
  const int q = nwg >> 3;
  const int nf = (flat & 7) * q + (flat >> 3);
  bx = nf % gx;
  const int r = nf / gx;
  by = r % gy;
  bz = r / gy;
}

// ---------------- fp32 -> bf16 weight conversion ----------------
__global__ __launch_bounds__(256) void f32_to_bf16(const float* __restrict__ in,
                                                   u16* __restrict__ out, int n) {
  int i = blockIdx.x * 256 + threadIdx.x;
  if (i < n) out[i] = f2bf(in[i]);
}

__global__ __launch_bounds__(256) void concat_bias(const float* __restrict__ a,
                                                   const float* __restrict__ b,
                                                   float* __restrict__ o) {
  int i = blockIdx.x * 256 + threadIdx.x;  // grid 4 -> 1024
  o[i] = (i < 512) ? a[i] : b[i - 512];
}

// ---------------- GroupNorm stats: one block per (b,g) ----------------
__global__ __launch_bounds__(256) void gn_stats(const float* __restrict__ x,
                                                float* __restrict__ stats) {
  const int bg = blockIdx.x;
  const float4* p4 = (const float4*)(x + (size_t)bg * (CPG_ * S_));
  float s = 0.f, ss = 0.f;
  const int tid = threadIdx.x;
  for (int i = tid; i < CPG_ * S_ / 4; i += 256) {
    float4 v = p4[i];
    s  += v.x + v.y + v.z + v.w;
    ss += v.x * v.x + v.y * v.y + v.z * v.z + v.w * v.w;
  }
#pragma unroll
  for (int o = 32; o; o >>= 1) { s += __shfl_xor(s, o, 64); ss += __shfl_xor(ss, o, 64); }
  __shared__ float sm[8];
  const int wid = tid >> 6, lane = tid & 63;
  if (lane == 0) { sm[wid * 2] = s; sm[wid * 2 + 1] = ss; }
  __syncthreads();
  if (tid == 0) {
    s  = sm[0] + sm[2] + sm[4] + sm[6];
    ss = sm[1] + sm[3] + sm[5] + sm[7];
    const float inv = 1.f / (float)(CPG_ * S_);
    float mu = s * inv;
    float var = ss * inv - mu * mu;
    stats[bg * 2]     = mu;
    stats[bg * 2 + 1] = rsqrtf(var + EPS_);
  }
}

// ---------------- normalize + transpose: x[b,c,s] -> ht[b*s, c] bf16 ----------------
__global__ __launch_bounds__(256) void gn_apply_t(const float* __restrict__ x,
                                                  const float* __restrict__ gamma,
                                                  const float* __restrict__ beta,
                                                  const float* __restrict__ stats,
                                                  u16* __restrict__ ht) {
  __shared__ float tile[32][33];
  const int b = blockIdx.z, c0 = blockIdx.y * 32, s0 = blockIdx.x * 32;
  const int tx = threadIdx.x, ty = threadIdx.y;
#pragma unroll
  for (int i = 0; i < 4; ++i) {
    const int c  = c0 + ty + i * 8;
    const float mu = stats[(b * G_ + (c >> 4)) * 2];
    const float rs = stats[(b * G_ + (c >> 4)) * 2 + 1];
    const float v  = x[((size_t)b * C_ + c) * S_ + s0 + tx];
    tile[ty + i * 8][tx] = (v - mu) * rs * gamma[c] + beta[c];
  }
  __syncthreads();
#pragma unroll
  for (int i = 0; i < 4; ++i) {
    const int s = s0 + ty + i * 8;
    ht[((size_t)b * S_ + s) * C_ + c0 + tx] = f2bf(tile[tx][ty + i * 8]);
  }
}

// ======== shared frag-read / MFMA macros (swizzled LDS, 16x16x32 bf16) ========
#define LDB4(SL)                                                             \
  _Pragma("unroll") for (int i = 0; i < 4; ++i)                              \
      bfr[i] = *(const bf16x8*)&Bs[(SL)][bbase + i * 512];
#define LDA4(SL, MH)                                                         \
  _Pragma("unroll") for (int i = 0; i < 4; ++i)                              \
      af[i] = *(const bf16x8*)&As[(SL)][abase + ((MH) * 4 + i) * 512];
#define MFMA16(MH) do {                                                      \
    __builtin_amdgcn_s_setprio(1);                                           \
    _Pragma("unroll") for (int mi = 0; mi < 4; ++mi)                         \
    _Pragma("unroll") for (int ni = 0; ni < 4; ++ni)                         \
      acc[(MH) * 4 + mi][ni] = __builtin_amdgcn_mfma_f32_16x16x32_bf16(      \
          af[mi], bfr[ni], acc[(MH) * 4 + mi][ni], 0, 0, 0);                 \
    __builtin_amdgcn_s_setprio(0);                                           \
  } while (0)

// ================= 256x256 GEMM, 2-slot ring, 2 phases/K-tile =================
// C[m,n] = alpha * sum_k A[m,k]*B[n,k] (+bias[n]); A,B bf16 K-contiguous.
// 512 thr = 8 waves (2m x 4n), per-wave 128x64 (8x4 frags of 16x16x32).
// LDS 64 KB -> 2 blocks/CU: TLP covers the vmcnt(0)+barrier drain (m97/m114).
// slot = kh parity; slot staged exactly one phase after its last reader.
template <int BIAS_MODE>
__global__ __launch_bounds__(512, 4) void gemm256(
    const u16* __restrict__ Ag, int lda, long sA,
    const u16* __restrict__ Bg, int ldb, long sB,
    u16* __restrict__ Cg, int ldc, long sC,
    const float* __restrict__ bias, float alpha, int K) {
  __shared__ u16 As[2][8192];
  __shared__ u16 Bs[2][8192];
  int bx, by, bz;
  xcd_swz(bx, by, bz);
  const u16* A  = Ag + (size_t)bz * sA;
  const u16* Bm = Bg + (size_t)bz * sB;
  u16* Cb = Cg + (size_t)bz * sC;
  const int bm = by * 256, bn = bx * 256;
  const int tid = threadIdx.x;
  const int wid = tid >> 6, lane = tid & 63;
  const int wm = (wid >> 2) * 128, wn = (wid & 3) * 64;
  const int lr = lane & 15, lh = lane >> 4;

  // staging: lane covers (row = wid*16 + lane>>2 [+128], phys granule lane&3)
  const int srow = wid * 16 + (lane >> 2);
  const int sg   = (lane & 3) ^ ((srow >> 1) & 3);
  const u16* Asrc  = A  + (size_t)(bm + srow) * lda + sg * 8;
  const u16* Asrc2 = Asrc + (size_t)128 * lda;
  const u16* Bsrc  = Bm + (size_t)(bn + srow) * ldb + sg * 8;
  const u16* Bsrc2 = Bsrc + (size_t)128 * ldb;

  const int swz   = (lh ^ ((lr >> 1) & 3)) << 3;
  const int abase = (wm + lr) * 32 + swz;
  const int bbase = (wn + lr) * 32 + swz;

  float bias_v[4] = {0.f, 0.f, 0.f, 0.f};
  if (BIAS_MODE == 1) {
#pragma unroll
    for (int nf = 0; nf < 4; ++nf) bias_v[nf] = bias[bn + wn + nf * 16 + lr];
  }

  f32x4 acc[8][4];
  const f32x4 zero = {0.f, 0.f, 0.f, 0.f};
#pragma unroll
  for (int i = 0; i < 8; ++i)
#pragma unroll
    for (int j = 0; j < 4; ++j) acc[i][j] = zero;

#define STAGE2(T, KS) do {                                                   \
    const size_t _ko = (size_t)(T) * 64 + (KS) * 32;                         \
    g2lds16(Asrc + _ko,  &As[(KS)][wid * 512]);                              \
    g2lds16(Asrc2 + _ko, &As[(KS)][4096 + wid * 512]);                       \
    g2lds16(Bsrc + _ko,  &Bs[(KS)][wid * 512]);                              \
    g2lds16(Bsrc2 + _ko, &Bs[(KS)][4096 + wid * 512]);                       \
  } while (0)

  STAGE2(0, 0);
  const int nt = K >> 6;
  for (int t = 0; t < nt; ++t) {
    bf16x8 bfr[4], af[4];
    // ---- phase A: compute slot0 (kh0), stage this tile's kh1 into slot1
    WAITV0;            // own slot0 stages (issued 1 phase ago) complete
    BAR(); SCHED0();   // all waves' stages complete; slot1 readers done
    STAGE2(t, 1);
    LDB4(0);
    LDA4(0, 0); MFMA16(0);
    LDA4(0, 1); MFMA16(1);
    // ---- phase B: compute slot1 (kh1), stage next tile's kh0 into slot0
    WAITV0;
    BAR(); SCHED0();
    if (t + 1 < nt) STAGE2(t + 1, 0);
    LDB4(1);
    LDA4(1, 0); MFMA16(0);
    LDA4(1, 1); MFMA16(1);
  }
#undef STAGE2
  SCHED0();

#pragma unroll
  for (int mf = 0; mf < 8; ++mf) {
    const int row0 = bm + wm + mf * 16 + lh * 4;
#pragma unroll
    for (int nf = 0; nf < 4; ++nf) {
      const int col = bn + wn + nf * 16 + lr;
#pragma unroll
      for (int r = 0; r < 4; ++r)
        Cb[(size_t)(row0 + r) * ldc + col] = f2bf(acc[mf][nf][r] * alpha + bias_v[nf]);
    }
  }
}

// ============ 256x128 GEMM, 2-slot ring, 2 phases/K-tile (PV & QK-proj) ============
// 512 thr = 8 waves (4m x 2n), per-wave 64x64 (4x4 frags). LDS 48 KB -> 2 blocks/CU.
template <int BIAS_MODE>
__global__ __launch_bounds__(512, 4) void gemm256n128(
    const u16* __restrict__ Ag, int lda, long sA,
    const u16* __restrict__ Bg, int ldb, long sB,
    u16* __restrict__ Cg, int ldc, long sC,
    const float* __restrict__ bias, float alpha, int K) {
  __shared__ u16 As[2][8192];
  __shared__ u16 Bs[2][4096];
  int bx, by, bz;
  xcd_swz(bx, by, bz);
  const u16* A  = Ag + (size_t)bz * sA;
  const u16* Bm = Bg + (size_t)bz * sB;
  u16* Cb = Cg + (size_t)bz * sC;
  const int bm = by * 256, bn = bx * 128;
  const int tid = threadIdx.x;
  const int wid = tid >> 6, lane = tid & 63;
  const int wm = (wid >> 1) * 64, wn = (wid & 1) * 64;
  const int lr = lane & 15, lh = lane >> 4;

  const int srow = wid * 16 + (lane >> 2);
  const int sg   = (lane & 3) ^ ((srow >> 1) & 3);
  const u16* Asrc  = A  + (size_t)(bm + srow) * lda + sg * 8;
  const u16* Asrc2 = Asrc + (size_t)128 * lda;
  const u16* Bsrc  = Bm + (size_t)(bn + srow) * ldb + sg * 8;

  const int swz   = (lh ^ ((lr >> 1) & 3)) << 3;
  const int abase = (wm + lr) * 32 + swz;
  const int bbase = (wn + lr) * 32 + swz;

  float bias_v[4] = {0.f, 0.f, 0.f, 0.f};
  if (BIAS_MODE == 1) {
#pragma unroll
    for (int nf = 0; nf < 4; ++nf) bias_v[nf] = bias[bn + wn + nf * 16 + lr];
  }

  f32x4 acc[4][4];
  const f32x4 zero = {0.f, 0.f, 0.f, 0.f};
#pragma unroll
  for (int i = 0; i < 4; ++i)
#pragma unroll
    for (int j = 0; j < 4; ++j) acc[i][j] = zero;

#define PSTG(T, KS) do {                                                     \
    const size_t _ko = (size_t)(T) * 64 + (KS) * 32;                         \
    g2lds16(Asrc + _ko,  &As[(KS)][wid * 512]);                              \
    g2lds16(Asrc2 + _ko, &As[(KS)][4096 + wid * 512]);                       \
    g2lds16(Bsrc + _ko,  &Bs[(KS)][wid * 512]);                              \
  } while (0)

  PSTG(0, 0);
  const int nt = K >> 6;
  for (int t = 0; t < nt; ++t) {
    bf16x8 bfr[4], af[4];
    // ---- phase A (kh0)
    WAITV0;
    BAR(); SCHED0();
    PSTG(t, 1);
    LDB4(0);
    LDA4(0, 0);
    MFMA16(0);
    // ---- phase B (kh1)
    WAITV0;
    BAR(); SCHED0();
    if (t + 1 < nt) PSTG(t + 1, 0);
    LDB4(1);
    LDA4(1, 0);
    MFMA16(0);
  }
#undef PSTG
  SCHED0();

#pragma unroll
  for (int mf = 0; mf < 4; ++mf) {
    const int row0 = bm + wm + mf * 16 + lh * 4;
#pragma unroll
    for (int nf = 0; nf < 4; ++nf) {
      const int col = bn + wn + nf * 16 + lr;
#pragma unroll
      for (int r = 0; r < 4; ++r)
        Cb[(size_t)(row0 + r) * ldc + col] = f2bf(acc[mf][nf][r] * alpha + bias_v[nf]);
    }
  }
}

// ---------------- old 128x128 GEMM (kept for V and out-proj) ----------------
#define GBM 128
#define GBN 128
#define GBK 64

template <int BIAS_MODE, int OUT_MODE>
__global__ __launch_bounds__(256) void gemm_abT(
    const u16* __restrict__ Ag, int lda, long sA,
    const u16* __restrict__ Bg, int ldb, long sB,
    void* __restrict__ Cg, int ldc, long sC,
    const float* __restrict__ bias, float alpha,
    const float* __restrict__ xres, int K) {
  __shared__ u16 As[GBM * GBK];
  __shared__ u16 Bs[GBN * GBK];
  const int bz = blockIdx.z;
  const u16* A    = Ag + (size_t)bz * sA;
  const u16* Bmat = Bg + (size_t)bz * sB;
  const int bm = blockIdx.y * GBM, bn = blockIdx.x * GBN;
  const int tid = threadIdx.x;
  const int wid = tid >> 6, lane = tid & 63;
  const int wm = (wid >> 1) * 64, wn = (wid & 1) * 64;
  const int lr = lane & 15, lh = lane >> 4;
  const int srow = lane >> 3, scol = (lane & 7) * 8;

  f32x4 acc[4][4];
  const f32x4 zero = {0.f, 0.f, 0.f, 0.f};
#pragma unroll
  for (int i = 0; i < 4; ++i)
#pragma unroll
    for (int j = 0; j < 4; ++j) acc[i][j] = zero;

  for (int k0 = 0; k0 < K; k0 += GBK) {
    __syncthreads();
#pragma unroll
    for (int i = 0; i < 4; ++i) {
      const int chunk = wid * 4 + i;
      const int row   = chunk * 8 + srow;
      g2lds16(A    + (size_t)(bm + row) * lda + (k0 + scol), &As[chunk * 512]);
      g2lds16(Bmat + (size_t)(bn + row) * ldb + (k0 + scol), &Bs[chunk * 512]);
    }
    __syncthreads();
#pragma unroll
    for (int ks = 0; ks < 2; ++ks) {
      bf16x8 a_[4], b_[4];
#pragma unroll
      for (int m = 0; m < 4; ++m)
        a_[m] = *(const bf16x8*)&As[(wm + m * 16 + lr) * GBK + ks * 32 + lh * 8];
#pragma unroll
      for (int n = 0; n < 4; ++n)
        b_[n] = *(const bf16x8*)&Bs[(wn + n * 16 + lr) * GBK + ks * 32 + lh * 8];
#pragma unroll
      for (int m = 0; m < 4; ++m)
#pragma unroll
        for (int n = 0; n < 4; ++n)
          acc[m][n] = __builtin_amdgcn_mfma_f32_16x16x32_bf16(a_[m], b_[n], acc[m][n], 0, 0, 0);
    }
  }

  if (OUT_MODE == 0) {
    u16* Cb = (u16*)Cg + (size_t)bz * sC;
#pragma unroll
    for (int m = 0; m < 4; ++m) {
      const int row0 = bm + wm + m * 16 + lh * 4;
#pragma unroll
      for (int n = 0; n < 4; ++n) {
        const int col = bn + wn + n * 16 + lr;
        float bn_ = (BIAS_MODE == 1) ? bias[col] : 0.f;
#pragma unroll
        for (int r = 0; r < 4; ++r) {
          float bb = (BIAS_MODE == 2) ? bias[row0 + r] : bn_;
          Cb[(size_t)(row0 + r) * ldc + col] = f2bf(acc[m][n][r] * alpha + bb);
        }
      }
    }
  } else {
    float* Ob = (float*)Cg;
#pragma unroll
    for (int m = 0; m < 4; ++m) {
      const int row0 = bm + wm + m * 16 + lh * 4;
#pragma unroll
      for (int n = 0; n < 4; ++n) {
        const int col = bn + wn + n * 16 + lr;
        const int bb = col >> 12, sp = col & (S_ - 1);
#pragma unroll
        for (int r = 0; r < 4; ++r) {
          const int o = row0 + r;
          const size_t idx = ((size_t)bb * C_ + o) * S_ + sp;
          Ob[idx] = acc[m][n][r] * alpha + bias[o] + xres[idx];
        }
      }
    }
  }
}

// ---------------- row softmax, in place on bf16 scores ----------------
__global__ __launch_bounds__(256) void softmax_rows(u16* __restrict__ sc) {
  const size_t base = ((size_t)blockIdx.y * S_ + blockIdx.x) * S_;
  uint4* r4 = (uint4*)(sc + base);
  const int tid = threadIdx.x;
  uint4 u0 = r4[tid], u1 = r4[tid + 256];
  float f[16];
  {
    const unsigned* pu = (const unsigned*)&u0;
    const unsigned* pv = (const unsigned*)&u1;
#pragma unroll
    for (int i = 0; i < 4; ++i) {
      f[2 * i]     = bf2f((u16)(pu[i] & 0xffffu));
      f[2 * i + 1] = bf2f((u16)(pu[i] >> 16));
      f[8 + 2 * i]     = bf2f((u16)(pv[i] & 0xffffu));
      f[8 + 2 * i + 1] = bf2f((u16)(pv[i] >> 16));
    }
  }
  float mx = f[0];
#pragma unroll
  for (int i = 1; i < 16; ++i) mx = fmaxf(mx, f[i]);
#pragma unroll
  for (int o = 32; o; o >>= 1) mx = fmaxf(mx, __shfl_xor(mx, o, 64));
  __shared__ float red[8];
  const int wid = tid >> 6, lane = tid & 63;
  if (lane == 0) red[wid] = mx;
  __syncthreads();
  mx = fmaxf(fmaxf(red[0], red[1]), fmaxf(red[2], red[3]));
  float s = 0.f;
#pragma unroll
  for (int i = 0; i < 16; ++i) { f[i] = __expf(f[i] - mx); s += f[i]; }
#pragma unroll
  for (int o = 32; o; o >>= 1) s += __shfl_xor(s, o, 64);
  if (lane == 0) red[4 + wid] = s;
  __syncthreads();
  s = red[4] + red[5] + red[6] + red[7];
  const float inv = 1.f / s;
  unsigned o0[4], o1[4];
#pragma unroll
  for (int i = 0; i < 4; ++i) {
    o0[i] = (unsigned)f2bf(f[2 * i] * inv)     | ((unsigned)f2bf(f[2 * i + 1] * inv) << 16);
    o1[i] = (unsigned)f2bf(f[8 + 2 * i] * inv) | ((unsigned)f2bf(f[8 + 2 * i + 1] * inv) << 16);
  }
  r4[tid]       = *(uint4*)o0;
  r4[tid + 256] = *(uint4*)o1;
}

extern "C" void kernel_launch(void* const* d_in, const int* in_sizes, int n_in,
                              void* d_out, int out_size, void* d_ws, size_t ws_size,
                              hipStream_t stream) {
  const float* x     = (const float*)d_in[0];
  const float* gamma = (const float*)d_in[1];
  const float* beta  = (const float*)d_in[2];
  const float* wq = (const float*)d_in[3];
  const float* bq = (const float*)d_in[4];
  const float* wk = (const float*)d_in[5];
  const float* bk = (const float*)d_in[6];
  const float* wv = (const float*)d_in[7];
  const float* bv = (const float*)d_in[8];
  const float* wo = (const float*)d_in[9];
  const float* bo = (const float*)d_in[10];
  float* out = (float*)d_out;

  // ws: stats 1KB | wq,wk,wv,wo bf16 (4x512KB) | bqk 4KB | ht 16MB | qkt 32MB | vv 16MB | sc 128MB
  char* ws = (char*)d_ws;
  float* stats = (float*)ws;
  u16* wqb = (u16*)(ws + 1024);
  u16* wkb = wqb + 262144;   // contiguous after wqb -> [wq;wk] is one 1024x512 matrix
  u16* wvb = wkb + 262144;
  u16* wob = wvb + 262144;
  float* bqk = (float*)(wob + 262144);
  u16* ht  = (u16*)((char*)bqk + 4096);  // [B*S, C]
  u16* qkt = ht + 8388608;               // [B*S, 1024]  (q | k)
  u16* vv  = qkt + 16777216;             // [C, B*S]
  u16* sc  = vv + 8388608;               // [B, S, S]
  u16* ha  = qkt;                        // hattnT reuses qkt (dead after scores)

  f32_to_bf16<<<1024, 256, 0, stream>>>(wq, wqb, 262144);
  f32_to_bf16<<<1024, 256, 0, stream>>>(wk, wkb, 262144);
  f32_to_bf16<<<1024, 256, 0, stream>>>(wv, wvb, 262144);
  f32_to_bf16<<<1024, 256, 0, stream>>>(wo, wob, 262144);
  concat_bias<<<4, 256, 0, stream>>>(bq, bk, bqk);

  gn_stats<<<128, 256, 0, stream>>>(x, stats);
  gn_apply_t<<<dim3(128, 16, 4), dim3(32, 8), 0, stream>>>(x, gamma, beta, stats, ht);

  // fused Q|K projection: qkt[bs, 0:512]=Q, [512:1024]=K  (256x128 tiles -> 512 blocks)
  gemm256n128<1><<<dim3(8, 64, 1), 512, 0, stream>>>(ht, 512, 0, wqb, 512, 0,
                                                     qkt, 1024, 0, bqk, 1.f, 512);
  // V[c, b*S+s] (old kernel)
  gemm_abT<2, 0><<<dim3(128, 4, 1), 256, 0, stream>>>(wvb, 512, 0, ht, 512, 0,
                                                      vv, 16384, 0, bv, 1.f, nullptr, 512);
  // scores[b,i,j] = scale * Q_b[i,:].K_b[j,:]
  gemm256<0><<<dim3(16, 16, 4), 512, 0, stream>>>(qkt, 1024, 4194304, qkt + 512, 1024, 4194304,
                                                  sc, 4096, 16777216, nullptr,
                                                  0.04419417382415922f, 512);
  softmax_rows<<<dim3(4096, 4), 256, 0, stream>>>(sc);
  // hattnT[b*S+i, c] = sum_j P_b[i,j] * V_b[c,j]   (256x128 tiles -> 256 blocks)
  gemm256n128<0><<<dim3(4, 16, 4), 512, 0, stream>>>(sc, 4096, 16777216, vv, 16384, 4096,
                                                     ha, 512, 2097152, nullptr, 1.f, 4096);
  // out[b,o,s] = Wo@hattn + bo + x  (old kernel, fused residual epilogue)
  gemm_abT<2, 1><<<dim3(128, 4, 1), 256, 0, stream>>>(wob, 512, 0, ha, 512, 0,
                                                      out, 0, 0, bo, 1.f, x, 512);
}

// Round 5
// 382.403 us; speedup vs baseline: 2.2442x; 2.2442x over previous
//
#include <hip/hip_runtime.h>

#define B_   4
#define C_   512
#define S_   4096
#define G_   32
#define CPG_ 16
#define EPS_ 1e-6f

typedef unsigned short u16;
typedef __bf16 bf16x8 __attribute__((ext_vector_type(8)));
typedef float  f32x4  __attribute__((ext_vector_type(4)));

__device__ __forceinline__ u16 f2bf(float f) {
  unsigned u = __float_as_uint(f);
  u += 0x7fffu + ((u >> 16) & 1u);   // RNE
  return (u16)(u >> 16);
}
__device__ __forceinline__ float bf2f(u16 h) {
  return __uint_as_float((unsigned)h << 16);
}

__device__ __forceinline__ void g2lds16(const void* g, void* l) {
  __builtin_amdgcn_global_load_lds(
      (const __attribute__((address_space(1))) void*)g,
      (__attribute__((address_space(3))) void*)l, 16, 0, 0);
}

#define BAR()    __builtin_amdgcn_s_barrier()
#define SCHED0() __builtin_amdgcn_sched_barrier(0)
#define WAITV6   asm volatile("s_waitcnt vmcnt(6)" ::: "memory")
#define WAITV0   asm volatile("s_waitcnt vmcnt(0)" ::: "memory")

// chunked XCD swizzle (bijective when nwg % 8 == 0 — all grids here satisfy it)
__device__ __forceinline__ void xcd_swz(int& bx, int& by, int& bz) {
  const int gx = gridDim.x, gy = gridDim.y;
  const int nwg = gx * gy * (int)gridDim.z;
  const int flat = blockIdx.x + gx * (blockIdx.y + gy * blockIdx.z);
  const int q = nwg >> 3;
  const int nf = (flat & 7) * q + (flat >> 3);
  bx = nf % gx;
  const int r = nf / gx;
  by = r % gy;
  bz = r / gy;
}

// ---------------- fp32 -> bf16 weight conversion ----------------
__global__ __launch_bounds__(256) void f32_to_bf16(const float* __restrict__ in,
                                                   u16* __restrict__ out, int n) {
  int i = blockIdx.x * 256 + threadIdx.x;
  if (i < n) out[i] = f2bf(in[i]);
}

__global__ __launch_bounds__(256) void concat_bias(const float* __restrict__ a,
                                                   const float* __restrict__ b,
                                                   float* __restrict__ o) {
  int i = blockIdx.x * 256 + threadIdx.x;  // grid 4 -> 1024
  o[i] = (i < 512) ? a[i] : b[i - 512];
}

// ---------------- GroupNorm stats: one block per (b,g) ----------------
__global__ __launch_bounds__(256) void gn_stats(const float* __restrict__ x,
                                                float* __restrict__ stats) {
  const int bg = blockIdx.x;
  const float4* p4 = (const float4*)(x + (size_t)bg * (CPG_ * S_));
  float s = 0.f, ss = 0.f;
  const int tid = threadIdx.x;
  for (int i = tid; i < CPG_ * S_ / 4; i += 256) {
    float4 v = p4[i];
    s  += v.x + v.y + v.z + v.w;
    ss += v.x * v.x + v.y * v.y + v.z * v.z + v.w * v.w;
  }
#pragma unroll
  for (int o = 32; o; o >>= 1) { s += __shfl_xor(s, o, 64); ss += __shfl_xor(ss, o, 64); }
  __shared__ float sm[8];
  const int wid = tid >> 6, lane = tid & 63;
  if (lane == 0) { sm[wid * 2] = s; sm[wid * 2 + 1] = ss; }
  __syncthreads();
  if (tid == 0) {
    s  = sm[0] + sm[2] + sm[4] + sm[6];
    ss = sm[1] + sm[3] + sm[5] + sm[7];
    const float inv = 1.f / (float)(CPG_ * S_);
    float mu = s * inv;
    float var = ss * inv - mu * mu;
    stats[bg * 2]     = mu;
    stats[bg * 2 + 1] = rsqrtf(var + EPS_);
  }
}

// ---------------- normalize + transpose: x[b,c,s] -> ht[b*s, c] bf16 ----------------
__global__ __launch_bounds__(256) void gn_apply_t(const float* __restrict__ x,
                                                  const float* __restrict__ gamma,
                                                  const float* __restrict__ beta,
                                                  const float* __restrict__ stats,
                                                  u16* __restrict__ ht) {
  __shared__ float tile[32][33];
  const int b = blockIdx.z, c0 = blockIdx.y * 32, s0 = blockIdx.x * 32;
  const int tx = threadIdx.x, ty = threadIdx.y;
#pragma unroll
  for (int i = 0; i < 4; ++i) {
    const int c  = c0 + ty + i * 8;
    const float mu = stats[(b * G_ + (c >> 4)) * 2];
    const float rs = stats[(b * G_ + (c >> 4)) * 2 + 1];
    const float v  = x[((size_t)b * C_ + c) * S_ + s0 + tx];
    tile[ty + i * 8][tx] = (v - mu) * rs * gamma[c] + beta[c];
  }
  __syncthreads();
#pragma unroll
  for (int i = 0; i < 4; ++i) {
    const int s = s0 + ty + i * 8;
    ht[((size_t)b * S_ + s) * C_ + c0 + tx] = f2bf(tile[tx][ty + i * 8]);
  }
}

// ============== 256x128 ring-of-3 GEMM (counted vmcnt, 1 barrier/K-tile) ==============
// C[m,n] = alpha * sum_k A[m,k]*B[n,k] (+bias); A,B bf16 K-contiguous (lda/ldb in u16).
// 512 thr = 8 waves (4m x 2n), per-wave 64x64 (4x4 frags of 16x16x32), acc = 64 VGPR.
// LDS: ring of 3 K-tiles, each split in 2 K-half sub-slots:
//   As[6][256*32] (96 KB) + Bs[6][128*32] (48 KB) = 144 KB -> 1 block/CU.
// Swizzle (proven 0-conflict in R3/R4): phys granule p = g ^ ((row>>1)&3).
// Ledger: tile t computes slot t%3; stages tile t+2 into slot (t-1)%3 (WAR-safe:
// its readers passed the tile-t barrier). 6 loads/thread/tile; vmcnt(6) at tile
// top drains tile t's stages, leaves t+1's in flight. 256 MFMA per barrier.
// BIAS_MODE: 0 none, 1 bias[n], 2 bias[m].
// OUT_MODE:  0 bf16 C[m*ldc+n]; 1 fp32 out[b,o,s] = acc + bias[m] + xres, n = b*S+s.
template <int BIAS_MODE, int OUT_MODE>
__global__ __launch_bounds__(512, 2) void gemm3r(
    const u16* __restrict__ Ag, int lda, long sA,
    const u16* __restrict__ Bg, int ldb, long sB,
    void* __restrict__ Cg, int ldc, long sC,
    const float* __restrict__ bias, float alpha,
    const float* __restrict__ xres, int K) {
  __shared__ u16 As[6][8192];
  __shared__ u16 Bs[6][4096];
  int bx, by, bz;
  xcd_swz(bx, by, bz);
  const u16* A  = Ag + (size_t)bz * sA;
  const u16* Bm = Bg + (size_t)bz * sB;
  const int bm = by * 256, bn = bx * 128;
  const int tid = threadIdx.x;
  const int wid = tid >> 6, lane = tid & 63;
  const int wm = (wid >> 1) * 64, wn = (wid & 1) * 64;
  const int lr = lane & 15, lh = lane >> 4;

  // staging: lane covers (row = wid*16 + lane>>2 [+128 for A's second half],
  //                       phys granule lane&3)
  const int srow = wid * 16 + (lane >> 2);
  const int sg   = (lane & 3) ^ ((srow >> 1) & 3);
  const u16* Asrc  = A  + (size_t)(bm + srow) * lda + sg * 8;
  const u16* Asrc2 = Asrc + (size_t)128 * lda;
  const u16* Bsrc  = Bm + (size_t)(bn + srow) * ldb + sg * 8;

  const int swz   = (lh ^ ((lr >> 1) & 3)) << 3;
  const int abase = (wm + lr) * 32 + swz;
  const int bbase = (wn + lr) * 32 + swz;

  f32x4 acc[4][4];
  const f32x4 zero = {0.f, 0.f, 0.f, 0.f};
#pragma unroll
  for (int i = 0; i < 4; ++i)
#pragma unroll
    for (int j = 0; j < 4; ++j) acc[i][j] = zero;

  // stage K-tile T (6 loads: A-kh0 x2, A-kh1 x2, B-kh0, B-kh1) into sub-slots SL,SL+1
#define STAGE6(SL, T) do {                                                   \
    const size_t _ko = (size_t)(T) * 64;                                     \
    g2lds16(Asrc  + _ko,      &As[(SL)][wid * 512]);                         \
    g2lds16(Asrc2 + _ko,      &As[(SL)][4096 + wid * 512]);                  \
    g2lds16(Asrc  + _ko + 32, &As[(SL) + 1][wid * 512]);                     \
    g2lds16(Asrc2 + _ko + 32, &As[(SL) + 1][4096 + wid * 512]);              \
    g2lds16(Bsrc  + _ko,      &Bs[(SL)][wid * 512]);                         \
    g2lds16(Bsrc  + _ko + 32, &Bs[(SL) + 1][wid * 512]);                     \
  } while (0)

  STAGE6(0, 0);
  STAGE6(2, 1);

  const int nt = K >> 6;
  int slc = 0, sln = 2, slp = 4;  // current / next / stage-target sub-slot pairs
  for (int t = 0; t < nt; ++t) {
    if (t + 1 < nt) { WAITV6; } else { WAITV0; }
    BAR(); SCHED0();
    if (t + 2 < nt) STAGE6(slp, t + 2);
    bf16x8 a0[4], a1[4], b0[4], b1[4];
#pragma unroll
    for (int i = 0; i < 4; ++i) {
      a0[i] = *(const bf16x8*)&As[slc][abase + i * 512];
      a1[i] = *(const bf16x8*)&As[slc + 1][abase + i * 512];
      b0[i] = *(const bf16x8*)&Bs[slc][bbase + i * 512];
      b1[i] = *(const bf16x8*)&Bs[slc + 1][bbase + i * 512];
    }
    __builtin_amdgcn_s_setprio(1);
#pragma unroll
    for (int mi = 0; mi < 4; ++mi)
#pragma unroll
      for (int ni = 0; ni < 4; ++ni)
        acc[mi][ni] = __builtin_amdgcn_mfma_f32_16x16x32_bf16(a0[mi], b0[ni], acc[mi][ni], 0, 0, 0);
#pragma unroll
    for (int mi = 0; mi < 4; ++mi)
#pragma unroll
      for (int ni = 0; ni < 4; ++ni)
        acc[mi][ni] = __builtin_amdgcn_mfma_f32_16x16x32_bf16(a1[mi], b1[ni], acc[mi][ni], 0, 0, 0);
    __builtin_amdgcn_s_setprio(0);
    const int tmp = slc; slc = sln; sln = slp; slp = tmp;
  }
#undef STAGE6
  SCHED0();

  if (OUT_MODE == 0) {
    u16* Cb = (u16*)Cg + (size_t)bz * sC;
#pragma unroll
    for (int mf = 0; mf < 4; ++mf) {
      const int row0 = bm + wm + mf * 16 + lh * 4;
#pragma unroll
      for (int nf = 0; nf < 4; ++nf) {
        const int col = bn + wn + nf * 16 + lr;
        const float bn_ = (BIAS_MODE == 1) ? bias[col] : 0.f;
#pragma unroll
        for (int r = 0; r < 4; ++r) {
          const float bb = (BIAS_MODE == 2) ? bias[row0 + r] : bn_;
          Cb[(size_t)(row0 + r) * ldc + col] = f2bf(acc[mf][nf][r] * alpha + bb);
        }
      }
    }
  } else {
    float* Ob = (float*)Cg;  // full [B,C,S] fp32 output, col = b*S + s
#pragma unroll
    for (int mf = 0; mf < 4; ++mf) {
      const int row0 = bm + wm + mf * 16 + lh * 4;
#pragma unroll
      for (int nf = 0; nf < 4; ++nf) {
        const int col = bn + wn + nf * 16 + lr;
        const int bb = col >> 12, sp = col & (S_ - 1);
#pragma unroll
        for (int r = 0; r < 4; ++r) {
          const int o = row0 + r;
          const size_t idx = ((size_t)bb * C_ + o) * S_ + sp;
          Ob[idx] = acc[mf][nf][r] * alpha + bias[o] + xres[idx];
        }
      }
    }
  }
}

// ---------------- row softmax, in place on bf16 scores ----------------
__global__ __launch_bounds__(256) void softmax_rows(u16* __restrict__ sc) {
  const size_t base = ((size_t)blockIdx.y * S_ + blockIdx.x) * S_;
  uint4* r4 = (uint4*)(sc + base);
  const int tid = threadIdx.x;
  uint4 u0 = r4[tid], u1 = r4[tid + 256];
  float f[16];
  {
    const unsigned* pu = (const unsigned*)&u0;
    const unsigned* pv = (const unsigned*)&u1;
#pragma unroll
    for (int i = 0; i < 4; ++i) {
      f[2 * i]     = bf2f((u16)(pu[i] & 0xffffu));
      f[2 * i + 1] = bf2f((u16)(pu[i] >> 16));
      f[8 + 2 * i]     = bf2f((u16)(pv[i] & 0xffffu));
      f[8 + 2 * i + 1] = bf2f((u16)(pv[i] >> 16));
    }
  }
  float mx = f[0];
#pragma unroll
  for (int i = 1; i < 16; ++i) mx = fmaxf(mx, f[i]);
#pragma unroll
  for (int o = 32; o; o >>= 1) mx = fmaxf(mx, __shfl_xor(mx, o, 64));
  __shared__ float red[8];
  const int wid = tid >> 6, lane = tid & 63;
  if (lane == 0) red[wid] = mx;
  __syncthreads();
  mx = fmaxf(fmaxf(red[0], red[1]), fmaxf(red[2], red[3]));
  float s = 0.f;
#pragma unroll
  for (int i = 0; i < 16; ++i) { f[i] = __expf(f[i] - mx); s += f[i]; }
#pragma unroll
  for (int o = 32; o; o >>= 1) s += __shfl_xor(s, o, 64);
  if (lane == 0) red[4 + wid] = s;
  __syncthreads();
  s = red[4] + red[5] + red[6] + red[7];
  const float inv = 1.f / s;
  unsigned o0[4], o1[4];
#pragma unroll
  for (int i = 0; i < 4; ++i) {
    o0[i] = (unsigned)f2bf(f[2 * i] * inv)     | ((unsigned)f2bf(f[2 * i + 1] * inv) << 16);
    o1[i] = (unsigned)f2bf(f[8 + 2 * i] * inv) | ((unsigned)f2bf(f[8 + 2 * i + 1] * inv) << 16);
  }
  r4[tid]       = *(uint4*)o0;
  r4[tid + 256] = *(uint4*)o1;
}

extern "C" void kernel_launch(void* const* d_in, const int* in_sizes, int n_in,
                              void* d_out, int out_size, void* d_ws, size_t ws_size,
                              hipStream_t stream) {
  const float* x     = (const float*)d_in[0];
  const float* gamma = (const float*)d_in[1];
  const float* beta  = (const float*)d_in[2];
  const float* wq = (const float*)d_in[3];
  const float* bq = (const float*)d_in[4];
  const float* wk = (const float*)d_in[5];
  const float* bk = (const float*)d_in[6];
  const float* wv = (const float*)d_in[7];
  const float* bv = (const float*)d_in[8];
  const float* wo = (const float*)d_in[9];
  const float* bo = (const float*)d_in[10];
  float* out = (float*)d_out;

  // ws: stats 1KB | wq,wk,wv,wo bf16 (4x512KB) | bqk 4KB | ht 16MB | qkt 32MB | vv 16MB | sc 128MB
  char* ws = (char*)d_ws;
  float* stats = (float*)ws;
  u16* wqb = (u16*)(ws + 1024);
  u16* wkb = wqb + 262144;   // contiguous after wqb -> [wq;wk] is one 1024x512 matrix
  u16* wvb = wkb + 262144;
  u16* wob = wvb + 262144;
  float* bqk = (float*)(wob + 262144);
  u16* ht  = (u16*)((char*)bqk + 4096);  // [B*S, C]
  u16* qkt = ht + 8388608;               // [B*S, 1024]  (q | k)
  u16* vv  = qkt + 16777216;             // [C, B*S]
  u16* sc  = vv + 8388608;               // [B, S, S]
  u16* ha  = qkt;                        // hattnT reuses qkt (dead after scores)

  f32_to_bf16<<<1024, 256, 0, stream>>>(wq, wqb, 262144);
  f32_to_bf16<<<1024, 256, 0, stream>>>(wk, wkb, 262144);
  f32_to_bf16<<<1024, 256, 0, stream>>>(wv, wvb, 262144);
  f32_to_bf16<<<1024, 256, 0, stream>>>(wo, wob, 262144);
  concat_bias<<<4, 256, 0, stream>>>(bq, bk, bqk);

  gn_stats<<<128, 256, 0, stream>>>(x, stats);
  gn_apply_t<<<dim3(128, 16, 4), dim3(32, 8), 0, stream>>>(x, gamma, beta, stats, ht);

  // fused Q|K projection: qkt[bs, 0:512]=Q, [512:1024]=K   (512 blocks)
  gemm3r<1, 0><<<dim3(8, 64, 1), 512, 0, stream>>>(ht, 512, 0, wqb, 512, 0,
                                                   qkt, 1024, 0, bqk, 1.f, nullptr, 512);
  // V[c, b*S+s]: bias per m (=c)                            (256 blocks)
  gemm3r<2, 0><<<dim3(128, 2, 1), 512, 0, stream>>>(wvb, 512, 0, ht, 512, 0,
                                                    vv, 16384, 0, bv, 1.f, nullptr, 512);
  // scores[b,i,j] = scale * Q_b[i,:].K_b[j,:]               (2048 blocks)
  gemm3r<0, 0><<<dim3(32, 16, 4), 512, 0, stream>>>(qkt, 1024, 4194304, qkt + 512, 1024, 4194304,
                                                    sc, 4096, 16777216, nullptr,
                                                    0.04419417382415922f, nullptr, 512);
  softmax_rows<<<dim3(4096, 4), 256, 0, stream>>>(sc);
  // hattnT[b*S+i, c] = sum_j P_b[i,j] * V_b[c,j]            (256 blocks)
  gemm3r<0, 0><<<dim3(4, 16, 4), 512, 0, stream>>>(sc, 4096, 16777216, vv, 16384, 4096,
                                                   ha, 512, 2097152, nullptr, 1.f, nullptr, 4096);
  // out[b,o,s] = Wo@hattn + bo + x  (fp32 + residual)       (256 blocks)
  gemm3r<2, 1><<<dim3(128, 2, 1), 512, 0, stream>>>(wob, 512, 0, ha, 512, 0,
                                                    out, 0, 0, bo, 1.f, x, 512);
}

// Round 7
// 318.729 us; speedup vs baseline: 2.6925x; 1.1998x over previous
//
#include <hip/hip_runtime.h>

#define B_   4
#define C_   512
#define S_   4096
#define G_   32
#define CPG_ 16
#define EPS_ 1e-6f

typedef unsigned short u16;
typedef __bf16 bf16x8 __attribute__((ext_vector_type(8)));
typedef float  f32x4  __attribute__((ext_vector_type(4)));

__device__ __forceinline__ u16 f2bf(float f) {
  unsigned u = __float_as_uint(f);
  u += 0x7fffu + ((u >> 16) & 1u);   // RNE
  return (u16)(u >> 16);
}
__device__ __forceinline__ float bf2f(u16 h) {
  return __uint_as_float((unsigned)h << 16);
}

__device__ __forceinline__ void g2lds16(const void* g, void* l) {
  __builtin_amdgcn_global_load_lds(
      (const __attribute__((address_space(1))) void*)g,
      (__attribute__((address_space(3))) void*)l, 16, 0, 0);
}

#define BAR()    __builtin_amdgcn_s_barrier()
#define SCHED0() __builtin_amdgcn_sched_barrier(0)
#define WAITV4   asm volatile("s_waitcnt vmcnt(4)" ::: "memory")
#define WAITV0   asm volatile("s_waitcnt vmcnt(0)" ::: "memory")
#define LGKM0    asm volatile("s_waitcnt lgkmcnt(0)" ::: "memory")

// chunked XCD swizzle (bijective when nwg % 8 == 0 — all grids here satisfy it)
__device__ __forceinline__ void xcd_swz(int& bx, int& by, int& bz) {
  const int gx = gridDim.x, gy = gridDim.y;
  const int nwg = gx * gy * (int)gridDim.z;
  const int flat = blockIdx.x + gx * (blockIdx.y + gy * blockIdx.z);
  const int q = nwg >> 3;
  const int nf = (flat & 7) * q + (flat >> 3);
  bx = nf % gx;
  const int r = nf / gx;
  by = r % gy;
  bz = r / gy;
}

// ---------------- fp32 -> bf16 weight conversion ----------------
__global__ __launch_bounds__(256) void f32_to_bf16(const float* __restrict__ in,
                                                   u16* __restrict__ out, int n) {
  int i = blockIdx.x * 256 + threadIdx.x;
  if (i < n) out[i] = f2bf(in[i]);
}

__global__ __launch_bounds__(256) void concat_bias(const float* __restrict__ a,
                                                   const float* __restrict__ b,
                                                   float* __restrict__ o) {
  int i = blockIdx.x * 256 + threadIdx.x;  // grid 4 -> 1024
  o[i] = (i < 512) ? a[i] : b[i - 512];
}

// ---------------- bf16 partial-sum add (PV split-K reduce) ----------------
__global__ __launch_bounds__(256) void add_bf16(const u16* __restrict__ a,
                                                const u16* __restrict__ b,
                                                u16* __restrict__ o) {
  const int i = blockIdx.x * 256 + threadIdx.x;
  const uint4 ua = ((const uint4*)a)[i];
  const uint4 ub = ((const uint4*)b)[i];
  const unsigned* pa = (const unsigned*)&ua;
  const unsigned* pb = (const unsigned*)&ub;
  unsigned r[4];
#pragma unroll
  for (int k = 0; k < 4; ++k) {
    const float lo = bf2f((u16)(pa[k] & 0xffffu)) + bf2f((u16)(pb[k] & 0xffffu));
    const float hi = bf2f((u16)(pa[k] >> 16)) + bf2f((u16)(pb[k] >> 16));
    r[k] = (unsigned)f2bf(lo) | ((unsigned)f2bf(hi) << 16);
  }
  ((uint4*)o)[i] = *(const uint4*)r;
}

// ---------------- GroupNorm stats: one block per (b,g) ----------------
__global__ __launch_bounds__(256) void gn_stats(const float* __restrict__ x,
                                                float* __restrict__ stats) {
  const int bg = blockIdx.x;
  const float4* p4 = (const float4*)(x + (size_t)bg * (CPG_ * S_));
  float s = 0.f, ss = 0.f;
  const int tid = threadIdx.x;
  for (int i = tid; i < CPG_ * S_ / 4; i += 256) {
    float4 v = p4[i];
    s  += v.x + v.y + v.z + v.w;
    ss += v.x * v.x + v.y * v.y + v.z * v.z + v.w * v.w;
  }
#pragma unroll
  for (int o = 32; o; o >>= 1) { s += __shfl_xor(s, o, 64); ss += __shfl_xor(ss, o, 64); }
  __shared__ float sm[8];
  const int wid = tid >> 6, lane = tid & 63;
  if (lane == 0) { sm[wid * 2] = s; sm[wid * 2 + 1] = ss; }
  __syncthreads();
  if (tid == 0) {
    s  = sm[0] + sm[2] + sm[4] + sm[6];
    ss = sm[1] + sm[3] + sm[5] + sm[7];
    const float inv = 1.f / (float)(CPG_ * S_);
    float mu = s * inv;
    float var = ss * inv - mu * mu;
    stats[bg * 2]     = mu;
    stats[bg * 2 + 1] = rsqrtf(var + EPS_);
  }
}

// ---------------- normalize + transpose: x[b,c,s] -> ht[b*s, c] bf16 ----------------
__global__ __launch_bounds__(256) void gn_apply_t(const float* __restrict__ x,
                                                  const float* __restrict__ gamma,
                                                  const float* __restrict__ beta,
                                                  const float* __restrict__ stats,
                                                  u16* __restrict__ ht) {
  __shared__ float tile[32][33];
  const int b = blockIdx.z, c0 = blockIdx.y * 32, s0 = blockIdx.x * 32;
  const int tx = threadIdx.x, ty = threadIdx.y;
#pragma unroll
  for (int i = 0; i < 4; ++i) {
    const int c  = c0 + ty + i * 8;
    const float mu = stats[(b * G_ + (c >> 4)) * 2];
    const float rs = stats[(b * G_ + (c >> 4)) * 2 + 1];
    const float v  = x[((size_t)b * C_ + c) * S_ + s0 + tx];
    tile[ty + i * 8][tx] = (v - mu) * rs * gamma[c] + beta[c];
  }
  __syncthreads();
#pragma unroll
  for (int i = 0; i < 4; ++i) {
    const int s = s0 + ty + i * 8;
    ht[((size_t)b * S_ + s) * C_ + c0 + tx] = f2bf(tile[tx][ty + i * 8]);
  }
}

// ================= 256x256 8-phase GEMM (m201 port, race-fixed ledger) =================
// C[m,n] = alpha * sum_k A[m,k]*B[n,k] (+bias[n]); A,B bf16 K-contiguous.
// 512 thr = 8 waves (2M x 4N), STRIDED frags: m-frag f at wm + f*32, n-frag g at
// wn + g*64 (wm=(wid>>2)*16, wn=(wid&3)*16). LDS As/Bs[2 dbuf][2 half][128][64] u16.
// Swizzle: phys granule = g ^ (row&7), both sides.
// RACE-FIX ledger: counted vmcnt drains are placed BEFORE the end-barrier of the
// phase preceding the reads (prologue, p3, p7), so every ds_read of a staged
// buffer is {all-waves-drained -> barrier} protected. Steady state: 12 loads in
// flight, drains to 4, never 0.
// ZMODE 1 = PV split-K: bz -> (b = bz>>1, kh = bz&1), hardcoded offsets.
template <int BIAS_MODE, int ZMODE>
__global__ __launch_bounds__(512, 2) void gemm8p(
    const u16* __restrict__ Ag, int lda, long sA,
    const u16* __restrict__ Bg, int ldb, long sB,
    u16* __restrict__ Cg, int ldc, long sC,
    const float* __restrict__ bias, float alpha, int K) {
  __shared__ u16 As[2][2][8192];
  __shared__ u16 Bs[2][2][8192];
  int bx, by, bz;
  xcd_swz(bx, by, bz);
  const u16 *A, *Bm;
  u16* Cb;
  if (ZMODE == 0) {
    A = Ag + (size_t)bz * sA; Bm = Bg + (size_t)bz * sB; Cb = Cg + (size_t)bz * sC;
  } else {  // PV split-K: A = P[b], cols kh*2048+; B = V rows, cols b*4096+kh*2048+
    const int b = bz >> 1, kh = bz & 1;
    A  = Ag + (size_t)b * 16777216 + (size_t)kh * 2048;
    Bm = Bg + (size_t)b * 4096 + (size_t)kh * 2048;
    Cb = Cg + (size_t)kh * 8388608 + (size_t)b * 2097152;
  }
  const int bm = by * 256, bn = bx * 256;
  const int tid = threadIdx.x;
  const int wid = tid >> 6, lane = tid & 63;
  const int wm = (wid >> 2) * 16, wn = (wid & 3) * 16;
  const int lr = lane & 15, lh = lane >> 4;
  const int x7 = lr & 7;
  const int g0 = (lh ^ x7) * 8, g1 = ((4 | lh) ^ x7) * 8;  // swizzled granule offs (kh=0/1)

  // staging: wave w covers rows w*8..w*8+7 (+64) of each half; pre-swizzled source
  const int sg = (lane & 7) ^ ((lane >> 3) & 7);
  const u16* Abase = A  + (size_t)(bm + wid * 8 + (lane >> 3)) * lda + sg * 8;
  const u16* Bbase = Bm + (size_t)(bn + wid * 8 + (lane >> 3)) * ldb + sg * 8;

#define STGA(D, H, T) do {                                                   \
    const u16* _s = Abase + (size_t)((H) * 128) * lda + (size_t)(T) * 64;    \
    g2lds16(_s,                    &As[D][H][wid * 512]);                    \
    g2lds16(_s + (size_t)64 * lda, &As[D][H][4096 + wid * 512]);             \
  } while (0)
#define STGB(D, H, T) do {                                                   \
    const u16* _s = Bbase + (size_t)((H) * 128) * ldb + (size_t)(T) * 64;    \
    g2lds16(_s,                    &Bs[D][H][wid * 512]);                    \
    g2lds16(_s + (size_t)64 * ldb, &Bs[D][H][4096 + wid * 512]);             \
  } while (0)

  // bias preload FIRST: its 4 loads are oldest, drained by the prologue vmcnt(4)
  float bias_v[4] = {0.f, 0.f, 0.f, 0.f};
  if (BIAS_MODE == 1) {
#pragma unroll
    for (int g = 0; g < 4; ++g) bias_v[g] = bias[bn + wn + g * 64 + lr];
  }
  SCHED0();

  f32x4 acc[8][4];
  const f32x4 zero = {0.f, 0.f, 0.f, 0.f};
#pragma unroll
  for (int i = 0; i < 8; ++i)
#pragma unroll
    for (int j = 0; j < 4; ++j) acc[i][j] = zero;

  bf16x8 a_[4][2], b_[4][2];

#define RDA(D, AH) do {                                                      \
    _Pragma("unroll") for (int i = 0; i < 4; ++i) {                          \
      const int _o = (wm + i * 32 + lr) * 64;                                \
      a_[i][0] = *(const bf16x8*)&As[D][AH][_o + g0];                        \
      a_[i][1] = *(const bf16x8*)&As[D][AH][_o + g1];                        \
    } } while (0)
#define RDBALL(D) do {                                                       \
    _Pragma("unroll") for (int j = 0; j < 4; ++j) {                          \
      const int _o = (wn + (j & 1) * 64 + lr) * 64;                          \
      b_[j][0] = *(const bf16x8*)&Bs[D][j >> 1][_o + g0];                    \
      b_[j][1] = *(const bf16x8*)&Bs[D][j >> 1][_o + g1];                    \
    } } while (0)
#define MM(AH, BH) do {                                                      \
    __builtin_amdgcn_s_setprio(1);                                           \
    _Pragma("unroll") for (int i = 0; i < 4; ++i)                            \
    _Pragma("unroll") for (int j = 0; j < 2; ++j) {                          \
      acc[(AH) * 4 + i][(BH) * 2 + j] = __builtin_amdgcn_mfma_f32_16x16x32_bf16( \
          a_[i][0], b_[(BH) * 2 + j][0], acc[(AH) * 4 + i][(BH) * 2 + j], 0, 0, 0); \
      acc[(AH) * 4 + i][(BH) * 2 + j] = __builtin_amdgcn_mfma_f32_16x16x32_bf16( \
          a_[i][1], b_[(BH) * 2 + j][1], acc[(AH) * 4 + i][(BH) * 2 + j], 0, 0, 0); \
    }                                                                        \
    __builtin_amdgcn_s_setprio(0);                                           \
  } while (0)
#define MID() SCHED0(); BAR(); LGKM0; SCHED0()

  // prologue: tile0 all 4 halves, then tile1 A0,B1; drain tile0 BEFORE the
  // barrier so every wave's stages have landed before any wave's p0 reads.
  STGA(0, 0, 0); STGB(0, 1, 0); STGA(0, 1, 0); STGB(0, 0, 0);
  STGA(1, 0, 1); STGB(1, 1, 1);
  WAITV4;
  BAR();

  const int nt = K >> 6;  // even, >= 4
  for (int i = 0; i < nt / 2; ++i) {
    const int t1 = 2 * i + 1, t2 = 2 * i + 2, t3 = 2 * i + 3;
    const bool s2 = t2 < nt, s3 = t3 < nt;
    // p0 (d0, A0,B0)
    RDA(0, 0); RDBALL(0);
    STGB(1, 0, t1);
    MID(); MM(0, 0); BAR();
    // p1 (d0, A0,B1)
    STGA(1, 1, t1);
    MID(); MM(0, 1); BAR();
    // p2 (d0, A1,B1)
    RDA(0, 1);
    if (s2) STGA(0, 0, t2);
    MID(); MM(1, 1); BAR();
    // p3 (d0, A1,B0) — drain d1's stages BEFORE the end barrier
    if (s2) STGB(0, 1, t2);
    MID(); MM(1, 0);
    if (s2) { WAITV4; } else { WAITV0; }
    BAR();
    // p4 (d1, A0,B0)
    RDA(1, 0); RDBALL(1);
    if (s2) STGA(0, 1, t2);
    MID(); MM(0, 0); BAR();
    // p5 (d1, A0,B1)
    if (s2) STGB(0, 0, t2);
    MID(); MM(0, 1); BAR();
    // p6 (d1, A1,B1)
    RDA(1, 1);
    if (s3) STGA(1, 0, t3);
    MID(); MM(1, 1); BAR();
    // p7 (d1, A1,B0) — drain next d0's stages BEFORE the end barrier
    if (s3) STGB(1, 1, t3);
    MID(); MM(1, 0);
    if (s3) { WAITV4; }
    BAR();
  }
#undef STGA
#undef STGB
#undef RDA
#undef RDBALL
#undef MM
#undef MID
  SCHED0();

#pragma unroll
  for (int f = 0; f < 8; ++f) {
    const int row0 = bm + wm + f * 32 + lh * 4;
#pragma unroll
    for (int g = 0; g < 4; ++g) {
      const int col = bn + wn + g * 64 + lr;
#pragma unroll
      for (int r = 0; r < 4; ++r)
        Cb[(size_t)(row0 + r) * ldc + col] = f2bf(acc[f][g][r] * alpha + bias_v[g]);
    }
  }
}

// ---------------- old 128x128 GEMM (kept for V-proj and out-proj) ----------------
#define GBM 128
#define GBN 128
#define GBK 64

template <int BIAS_MODE, int OUT_MODE>
__global__ __launch_bounds__(256) void gemm_abT(
    const u16* __restrict__ Ag, int lda, long sA,
    const u16* __restrict__ Bg, int ldb, long sB,
    void* __restrict__ Cg, int ldc, long sC,
    const float* __restrict__ bias, float alpha,
    const float* __restrict__ xres, int K) {
  __shared__ u16 As[GBM * GBK];
  __shared__ u16 Bs[GBN * GBK];
  const int bz = blockIdx.z;
  const u16* A    = Ag + (size_t)bz * sA;
  const u16* Bmat = Bg + (size_t)bz * sB;
  const int bm = blockIdx.y * GBM, bn = blockIdx.x * GBN;
  const int tid = threadIdx.x;
  const int wid = tid >> 6, lane = tid & 63;
  const int wm = (wid >> 1) * 64, wn = (wid & 1) * 64;
  const int lr = lane & 15, lh = lane >> 4;
  const int srow = lane >> 3, scol = (lane & 7) * 8;

  f32x4 acc[4][4];
  const f32x4 zero = {0.f, 0.f, 0.f, 0.f};
#pragma unroll
  for (int i = 0; i < 4; ++i)
#pragma unroll
    for (int j = 0; j < 4; ++j) acc[i][j] = zero;

  for (int k0 = 0; k0 < K; k0 += GBK) {
    __syncthreads();
#pragma unroll
    for (int i = 0; i < 4; ++i) {
      const int chunk = wid * 4 + i;
      const int row   = chunk * 8 + srow;
      g2lds16(A    + (size_t)(bm + row) * lda + (k0 + scol), &As[chunk * 512]);
      g2lds16(Bmat + (size_t)(bn + row) * ldb + (k0 + scol), &Bs[chunk * 512]);
    }
    __syncthreads();
#pragma unroll
    for (int ks = 0; ks < 2; ++ks) {
      bf16x8 a_[4], b_[4];
#pragma unroll
      for (int m = 0; m < 4; ++m)
        a_[m] = *(const bf16x8*)&As[(wm + m * 16 + lr) * GBK + ks * 32 + lh * 8];
#pragma unroll
      for (int n = 0; n < 4; ++n)
        b_[n] = *(const bf16x8*)&Bs[(wn + n * 16 + lr) * GBK + ks * 32 + lh * 8];
#pragma unroll
      for (int m = 0; m < 4; ++m)
#pragma unroll
        for (int n = 0; n < 4; ++n)
          acc[m][n] = __builtin_amdgcn_mfma_f32_16x16x32_bf16(a_[m], b_[n], acc[m][n], 0, 0, 0);
    }
  }

  if (OUT_MODE == 0) {
    u16* Cb = (u16*)Cg + (size_t)bz * sC;
#pragma unroll
    for (int m = 0; m < 4; ++m) {
      const int row0 = bm + wm + m * 16 + lh * 4;
#pragma unroll
      for (int n = 0; n < 4; ++n) {
        const int col = bn + wn + n * 16 + lr;
        float bn_ = (BIAS_MODE == 1) ? bias[col] : 0.f;
#pragma unroll
        for (int r = 0; r < 4; ++r) {
          float bb = (BIAS_MODE == 2) ? bias[row0 + r] : bn_;
          Cb[(size_t)(row0 + r) * ldc + col] = f2bf(acc[m][n][r] * alpha + bb);
        }
      }
    }
  } else {
    float* Ob = (float*)Cg;
#pragma unroll
    for (int m = 0; m < 4; ++m) {
      const int row0 = bm + wm + m * 16 + lh * 4;
#pragma unroll
      for (int n = 0; n < 4; ++n) {
        const int col = bn + wn + n * 16 + lr;
        const int bb = col >> 12, sp = col & (S_ - 1);
#pragma unroll
        for (int r = 0; r < 4; ++r) {
          const int o = row0 + r;
          const size_t idx = ((size_t)bb * C_ + o) * S_ + sp;
          Ob[idx] = acc[m][n][r] * alpha + bias[o] + xres[idx];
        }
      }
    }
  }
}

// ---------------- row softmax, in place on bf16 scores ----------------
__global__ __launch_bounds__(256) void softmax_rows(u16* __restrict__ sc) {
  const size_t base = ((size_t)blockIdx.y * S_ + blockIdx.x) * S_;
  uint4* r4 = (uint4*)(sc + base);
  const int tid = threadIdx.x;
  uint4 u0 = r4[tid], u1 = r4[tid + 256];
  float f[16];
  {
    const unsigned* pu = (const unsigned*)&u0;
    const unsigned* pv = (const unsigned*)&u1;
#pragma unroll
    for (int i = 0; i < 4; ++i) {
      f[2 * i]     = bf2f((u16)(pu[i] & 0xffffu));
      f[2 * i + 1] = bf2f((u16)(pu[i] >> 16));
      f[8 + 2 * i]     = bf2f((u16)(pv[i] & 0xffffu));
      f[8 + 2 * i + 1] = bf2f((u16)(pv[i] >> 16));
    }
  }
  float mx = f[0];
#pragma unroll
  for (int i = 1; i < 16; ++i) mx = fmaxf(mx, f[i]);
#pragma unroll
  for (int o = 32; o; o >>= 1) mx = fmaxf(mx, __shfl_xor(mx, o, 64));
  __shared__ float red[8];
  const int wid = tid >> 6, lane = tid & 63;
  if (lane == 0) red[wid] = mx;
  __syncthreads();
  mx = fmaxf(fmaxf(red[0], red[1]), fmaxf(red[2], red[3]));
  float s = 0.f;
#pragma unroll
  for (int i = 0; i < 16; ++i) { f[i] = __expf(f[i] - mx); s += f[i]; }
#pragma unroll
  for (int o = 32; o; o >>= 1) s += __shfl_xor(s, o, 64);
  if (lane == 0) red[4 + wid] = s;
  __syncthreads();
  s = red[4] + red[5] + red[6] + red[7];
  const float inv = 1.f / s;
  unsigned o0[4], o1[4];
#pragma unroll
  for (int i = 0; i < 4; ++i) {
    o0[i] = (unsigned)f2bf(f[2 * i] * inv)     | ((unsigned)f2bf(f[2 * i + 1] * inv) << 16);
    o1[i] = (unsigned)f2bf(f[8 + 2 * i] * inv) | ((unsigned)f2bf(f[8 + 2 * i + 1] * inv) << 16);
  }
  r4[tid]       = *(uint4*)o0;
  r4[tid + 256] = *(uint4*)o1;
}

extern "C" void kernel_launch(void* const* d_in, const int* in_sizes, int n_in,
                              void* d_out, int out_size, void* d_ws, size_t ws_size,
                              hipStream_t stream) {
  const float* x     = (const float*)d_in[0];
  const float* gamma = (const float*)d_in[1];
  const float* beta  = (const float*)d_in[2];
  const float* wq = (const float*)d_in[3];
  const float* bq = (const float*)d_in[4];
  const float* wk = (const float*)d_in[5];
  const float* bk = (const float*)d_in[6];
  const float* wv = (const float*)d_in[7];
  const float* bv = (const float*)d_in[8];
  const float* wo = (const float*)d_in[9];
  const float* bo = (const float*)d_in[10];
  float* out = (float*)d_out;

  // ws: stats 1KB | wq,wk,wv,wo bf16 (4x512KB) | bqk 4KB | ht 16MB | qkt 32MB | vv 16MB | sc 128MB
  char* ws = (char*)d_ws;
  float* stats = (float*)ws;
  u16* wqb = (u16*)(ws + 1024);
  u16* wkb = wqb + 262144;   // contiguous after wqb -> [wq;wk] is one 1024x512 matrix
  u16* wvb = wkb + 262144;
  u16* wob = wvb + 262144;
  float* bqk = (float*)(wob + 262144);
  u16* ht  = (u16*)((char*)bqk + 4096);  // [B*S, C]
  u16* qkt = ht + 8388608;               // [B*S, 1024] (q|k); later ha0|ha1 partials
  u16* vv  = qkt + 16777216;             // [C, B*S]; later ha final
  u16* sc  = vv + 8388608;               // [B, S, S]

  f32_to_bf16<<<1024, 256, 0, stream>>>(wq, wqb, 262144);
  f32_to_bf16<<<1024, 256, 0, stream>>>(wk, wkb, 262144);
  f32_to_bf16<<<1024, 256, 0, stream>>>(wv, wvb, 262144);
  f32_to_bf16<<<1024, 256, 0, stream>>>(wo, wob, 262144);
  concat_bias<<<4, 256, 0, stream>>>(bq, bk, bqk);

  gn_stats<<<128, 256, 0, stream>>>(x, stats);
  gn_apply_t<<<dim3(128, 16, 4), dim3(32, 8), 0, stream>>>(x, gamma, beta, stats, ht);

  // fused Q|K projection: qkt[bs, 0:512]=Q, [512:1024]=K   (256 blocks)
  gemm8p<1, 0><<<dim3(4, 64, 1), 512, 0, stream>>>(ht, 512, 0, wqb, 512, 0,
                                                   qkt, 1024, 0, bqk, 1.f, 512);
  // V[c, b*S+s]: bias per m (=c)                            (512 blocks)
  gemm_abT<2, 0><<<dim3(128, 4, 1), 256, 0, stream>>>(wvb, 512, 0, ht, 512, 0,
                                                      vv, 16384, 0, bv, 1.f, nullptr, 512);
  // scores[b,i,j] = scale * Q_b[i,:].K_b[j,:]               (1024 blocks)
  gemm8p<0, 0><<<dim3(16, 16, 4), 512, 0, stream>>>(qkt, 1024, 4194304, qkt + 512, 1024, 4194304,
                                                    sc, 4096, 16777216, nullptr,
                                                    0.04419417382415922f, 512);
  softmax_rows<<<dim3(4096, 4), 256, 0, stream>>>(sc);
  // PV split-K=2: partials ha0=qkt, ha1=qkt+8M               (256 blocks)
  gemm8p<0, 1><<<dim3(2, 16, 8), 512, 0, stream>>>(sc, 4096, 0, vv, 16384, 0,
                                                   qkt, 512, 0, nullptr, 1.f, 2048);
  // reduce partials -> ha in vv region (vv dead after PV)
  add_bf16<<<4096, 256, 0, stream>>>(qkt, qkt + 8388608, vv);
  // out[b,o,s] = Wo@hattn + bo + x  (fp32 + residual)        (512 blocks)
  gemm_abT<2, 1><<<dim3(128, 4, 1), 256, 0, stream>>>(wob, 512, 0, vv, 512, 0,
                                                      out, 0, 0, bo, 1.f, x, 512);
}

// Round 8
// 293.783 us; speedup vs baseline: 2.9211x; 1.0849x over previous
//
#include <hip/hip_runtime.h>

#define B_   4
#define C_   512
#define S_   4096
#define G_   32
#define CPG_ 16
#define EPS_ 1e-6f

typedef unsigned short u16;
typedef __bf16 bf16x8 __attribute__((ext_vector_type(8)));
typedef float  f32x4  __attribute__((ext_vector_type(4)));

__device__ __forceinline__ u16 f2bf(float f) {
  unsigned u = __float_as_uint(f);
  u += 0x7fffu + ((u >> 16) & 1u);   // RNE
  return (u16)(u >> 16);
}
__device__ __forceinline__ float bf2f(u16 h) {
  return __uint_as_float((unsigned)h << 16);
}

__device__ __forceinline__ void g2lds16(const void* g, void* l) {
  __builtin_amdgcn_global_load_lds(
      (const __attribute__((address_space(1))) void*)g,
      (__attribute__((address_space(3))) void*)l, 16, 0, 0);
}

#define BAR()    __builtin_amdgcn_s_barrier()
#define SCHED0() __builtin_amdgcn_sched_barrier(0)
#define WAITV4   asm volatile("s_waitcnt vmcnt(4)" ::: "memory")
#define WAITV0   asm volatile("s_waitcnt vmcnt(0)" ::: "memory")
#define LGKM0    asm volatile("s_waitcnt lgkmcnt(0)" ::: "memory")

// chunked XCD swizzle (bijective when nwg % 8 == 0 — all grids here satisfy it)
__device__ __forceinline__ void xcd_swz(int& bx, int& by, int& bz) {
  const int gx = gridDim.x, gy = gridDim.y;
  const int nwg = gx * gy * (int)gridDim.z;
  const int flat = blockIdx.x + gx * (blockIdx.y + gy * blockIdx.z);
  const int q = nwg >> 3;
  const int nf = (flat & 7) * q + (flat >> 3);
  bx = nf % gx;
  const int r = nf / gx;
  by = r % gy;
  bz = r / gy;
}

// ---------------- fp32 -> bf16 weight conversion ----------------
__global__ __launch_bounds__(256) void f32_to_bf16(const float* __restrict__ in,
                                                   u16* __restrict__ out, int n) {
  int i = blockIdx.x * 256 + threadIdx.x;
  if (i < n) out[i] = f2bf(in[i]);
}

__global__ __launch_bounds__(256) void concat_bias(const float* __restrict__ a,
                                                   const float* __restrict__ b,
                                                   float* __restrict__ o) {
  int i = blockIdx.x * 256 + threadIdx.x;  // grid 4 -> 1024
  o[i] = (i < 512) ? a[i] : b[i - 512];
}

// ---------------- softmax denominator: Lr[b,i] = 1/sum_jb partial ----------------
__global__ __launch_bounds__(256) void reduce_l(const float* __restrict__ p,
                                                float* __restrict__ lr) {
  const int i = blockIdx.x * 256 + threadIdx.x;   // 16384 = B*S
  const int b = i >> 12, row = i & 4095;
  float s = 0.f;
#pragma unroll
  for (int jb = 0; jb < 16; ++jb) s += p[((size_t)(b * 16 + jb) << 12) + row];
  lr[i] = 1.f / s;
}

// -------- PV split-K reduce + softmax normalize: o = (a+b)*Lr[row] --------
__global__ __launch_bounds__(256) void add_scale_bf16(const u16* __restrict__ a,
                                                      const u16* __restrict__ b,
                                                      const float* __restrict__ lr,
                                                      u16* __restrict__ o) {
  const int i = blockIdx.x * 256 + threadIdx.x;   // uint4 index (8 bf16)
  const size_t i8 = (size_t)i * 8;
  const int bi = (int)(i8 >> 21);          // 2M bf16 per batch
  const int row = (int)(i8 >> 9) & 4095;   // 512 bf16 per row
  const float sc = lr[bi * 4096 + row];
  const uint4 ua = ((const uint4*)a)[i];
  const uint4 ub = ((const uint4*)b)[i];
  const unsigned* pa = (const unsigned*)&ua;
  const unsigned* pb = (const unsigned*)&ub;
  unsigned r[4];
#pragma unroll
  for (int k = 0; k < 4; ++k) {
    const float lo = (bf2f((u16)(pa[k] & 0xffffu)) + bf2f((u16)(pb[k] & 0xffffu))) * sc;
    const float hi = (bf2f((u16)(pa[k] >> 16)) + bf2f((u16)(pb[k] >> 16))) * sc;
    r[k] = (unsigned)f2bf(lo) | ((unsigned)f2bf(hi) << 16);
  }
  ((uint4*)o)[i] = *(const uint4*)r;
}

// ---------------- GroupNorm stats: one block per (b,g) ----------------
__global__ __launch_bounds__(256) void gn_stats(const float* __restrict__ x,
                                                float* __restrict__ stats) {
  const int bg = blockIdx.x;
  const float4* p4 = (const float4*)(x + (size_t)bg * (CPG_ * S_));
  float s = 0.f, ss = 0.f;
  const int tid = threadIdx.x;
  for (int i = tid; i < CPG_ * S_ / 4; i += 256) {
    float4 v = p4[i];
    s  += v.x + v.y + v.z + v.w;
    ss += v.x * v.x + v.y * v.y + v.z * v.z + v.w * v.w;
  }
#pragma unroll
  for (int o = 32; o; o >>= 1) { s += __shfl_xor(s, o, 64); ss += __shfl_xor(ss, o, 64); }
  __shared__ float sm[8];
  const int wid = tid >> 6, lane = tid & 63;
  if (lane == 0) { sm[wid * 2] = s; sm[wid * 2 + 1] = ss; }
  __syncthreads();
  if (tid == 0) {
    s  = sm[0] + sm[2] + sm[4] + sm[6];
    ss = sm[1] + sm[3] + sm[5] + sm[7];
    const float inv = 1.f / (float)(CPG_ * S_);
    float mu = s * inv;
    float var = ss * inv - mu * mu;
    stats[bg * 2]     = mu;
    stats[bg * 2 + 1] = rsqrtf(var + EPS_);
  }
}

// ---------------- normalize + transpose: x[b,c,s] -> ht[b*s, c] bf16 ----------------
__global__ __launch_bounds__(256) void gn_apply_t(const float* __restrict__ x,
                                                  const float* __restrict__ gamma,
                                                  const float* __restrict__ beta,
                                                  const float* __restrict__ stats,
                                                  u16* __restrict__ ht) {
  __shared__ float tile[32][33];
  const int b = blockIdx.z, c0 = blockIdx.y * 32, s0 = blockIdx.x * 32;
  const int tx = threadIdx.x, ty = threadIdx.y;
#pragma unroll
  for (int i = 0; i < 4; ++i) {
    const int c  = c0 + ty + i * 8;
    const float mu = stats[(b * G_ + (c >> 4)) * 2];
    const float rs = stats[(b * G_ + (c >> 4)) * 2 + 1];
    const float v  = x[((size_t)b * C_ + c) * S_ + s0 + tx];
    tile[ty + i * 8][tx] = (v - mu) * rs * gamma[c] + beta[c];
  }
  __syncthreads();
#pragma unroll
  for (int i = 0; i < 4; ++i) {
    const int s = s0 + ty + i * 8;
    ht[((size_t)b * S_ + s) * C_ + c0 + tx] = f2bf(tile[tx][ty + i * 8]);
  }
}

// ================= 256x256 8-phase GEMM (race-fixed ledger) =================
// C[m,n] = alpha * sum_k A[m,k]*B[n,k] (+bias[n]); A,B bf16 K-contiguous.
// 512 thr = 8 waves (2M x 4N), strided frags: m-frag f at wm+f*32, n-frag g at
// wn+g*64. LDS As/Bs[2 dbuf][2 half][128][64] u16; swizzle phys granule = g^(row&7).
// Ledger: counted vmcnt(4) drains BEFORE the end-barrier of p3/p7 (+prologue), so
// every staged-buffer read is {all-waves-drained -> barrier} protected. Steady
// state 12 loads in flight, drains to 4, never 0.
// B-frag reads split per half (BH0 at p0/p4, BH1 at p1/p5) to spread LDS load.
// ZMODE 1 = PV split-K: bz -> (b = bz>>1, kh = bz&1), hardcoded offsets.
// SMAX 1 = scores epilogue: write exp(alpha*acc) bf16 + per-block row-sum partials.
template <int BIAS_MODE, int ZMODE, int SMAX>
__global__ __launch_bounds__(512, 2) void gemm8p(
    const u16* __restrict__ Ag, int lda, long sA,
    const u16* __restrict__ Bg, int ldb, long sB,
    u16* __restrict__ Cg, int ldc, long sC,
    const float* __restrict__ bias, float alpha, int K,
    float* __restrict__ smx) {
  __shared__ u16 As[2][2][8192];
  __shared__ u16 Bs[2][2][8192];
  __shared__ float ps[4][256];
  int bx, by, bz;
  xcd_swz(bx, by, bz);
  const u16 *A, *Bm;
  u16* Cb;
  if (ZMODE == 0) {
    A = Ag + (size_t)bz * sA; Bm = Bg + (size_t)bz * sB; Cb = Cg + (size_t)bz * sC;
  } else {  // PV split-K: A = P[b], cols kh*2048+; B = V rows, cols b*4096+kh*2048+
    const int b = bz >> 1, kh = bz & 1;
    A  = Ag + (size_t)b * 16777216 + (size_t)kh * 2048;
    Bm = Bg + (size_t)b * 4096 + (size_t)kh * 2048;
    Cb = Cg + (size_t)kh * 8388608 + (size_t)b * 2097152;
  }
  const int bm = by * 256, bn = bx * 256;
  const int tid = threadIdx.x;
  const int wid = tid >> 6, lane = tid & 63;
  const int wm = (wid >> 2) * 16, wn = (wid & 3) * 16;
  const int lr = lane & 15, lh = lane >> 4;
  const int x7 = lr & 7;
  const int g0 = (lh ^ x7) * 8, g1 = ((4 | lh) ^ x7) * 8;  // swizzled granule offs (kh=0/1)

  // staging: wave w covers rows w*8..w*8+7 (+64) of each half; pre-swizzled source
  const int sg = (lane & 7) ^ ((lane >> 3) & 7);
  const u16* Abase = A  + (size_t)(bm + wid * 8 + (lane >> 3)) * lda + sg * 8;
  const u16* Bbase = Bm + (size_t)(bn + wid * 8 + (lane >> 3)) * ldb + sg * 8;

#define STGA(D, H, T) do {                                                   \
    const u16* _s = Abase + (size_t)((H) * 128) * lda + (size_t)(T) * 64;    \
    g2lds16(_s,                    &As[D][H][wid * 512]);                    \
    g2lds16(_s + (size_t)64 * lda, &As[D][H][4096 + wid * 512]);             \
  } while (0)
#define STGB(D, H, T) do {                                                   \
    const u16* _s = Bbase + (size_t)((H) * 128) * ldb + (size_t)(T) * 64;    \
    g2lds16(_s,                    &Bs[D][H][wid * 512]);                    \
    g2lds16(_s + (size_t)64 * ldb, &Bs[D][H][4096 + wid * 512]);             \
  } while (0)

  // bias preload FIRST: its 4 loads are oldest, drained by the prologue vmcnt(4)
  float bias_v[4] = {0.f, 0.f, 0.f, 0.f};
  if (BIAS_MODE == 1) {
#pragma unroll
    for (int g = 0; g < 4; ++g) bias_v[g] = bias[bn + wn + g * 64 + lr];
  }
  SCHED0();

  f32x4 acc[8][4];
  const f32x4 zero = {0.f, 0.f, 0.f, 0.f};
#pragma unroll
  for (int i = 0; i < 8; ++i)
#pragma unroll
    for (int j = 0; j < 4; ++j) acc[i][j] = zero;

  bf16x8 a_[4][2], b_[4][2];

#define RDA(D, AH) do {                                                      \
    _Pragma("unroll") for (int i = 0; i < 4; ++i) {                          \
      const int _o = (wm + i * 32 + lr) * 64;                                \
      a_[i][0] = *(const bf16x8*)&As[D][AH][_o + g0];                        \
      a_[i][1] = *(const bf16x8*)&As[D][AH][_o + g1];                        \
    } } while (0)
#define RDB(D, BH) do {                                                      \
    _Pragma("unroll") for (int j = 0; j < 2; ++j) {                          \
      const int _o = (wn + j * 64 + lr) * 64;                                \
      b_[(BH) * 2 + j][0] = *(const bf16x8*)&Bs[D][BH][_o + g0];             \
      b_[(BH) * 2 + j][1] = *(const bf16x8*)&Bs[D][BH][_o + g1];             \
    } } while (0)
#define MM(AH, BH) do {                                                      \
    __builtin_amdgcn_s_setprio(1);                                           \
    _Pragma("unroll") for (int i = 0; i < 4; ++i)                            \
    _Pragma("unroll") for (int j = 0; j < 2; ++j) {                          \
      acc[(AH) * 4 + i][(BH) * 2 + j] = __builtin_amdgcn_mfma_f32_16x16x32_bf16( \
          a_[i][0], b_[(BH) * 2 + j][0], acc[(AH) * 4 + i][(BH) * 2 + j], 0, 0, 0); \
      acc[(AH) * 4 + i][(BH) * 2 + j] = __builtin_amdgcn_mfma_f32_16x16x32_bf16( \
          a_[i][1], b_[(BH) * 2 + j][1], acc[(AH) * 4 + i][(BH) * 2 + j], 0, 0, 0); \
    }                                                                        \
    __builtin_amdgcn_s_setprio(0);                                           \
  } while (0)
#define MID() SCHED0(); BAR(); LGKM0; SCHED0()

  // prologue: tile0 all 4 halves, then tile1 A0,B1; drain tile0 BEFORE the barrier
  STGA(0, 0, 0); STGB(0, 1, 0); STGA(0, 1, 0); STGB(0, 0, 0);
  STGA(1, 0, 1); STGB(1, 1, 1);
  WAITV4;
  BAR();

  const int nt = K >> 6;  // even, >= 4
  for (int i = 0; i < nt / 2; ++i) {
    const int t1 = 2 * i + 1, t2 = 2 * i + 2, t3 = 2 * i + 3;
    const bool s2 = t2 < nt, s3 = t3 < nt;
    // p0 (d0, A0,B0)
    RDA(0, 0); RDB(0, 0);
    STGB(1, 0, t1);
    MID(); MM(0, 0); BAR();
    // p1 (d0, A0,B1)
    RDB(0, 1);
    STGA(1, 1, t1);
    MID(); MM(0, 1); BAR();
    // p2 (d0, A1,B1)
    RDA(0, 1);
    if (s2) STGA(0, 0, t2);
    MID(); MM(1, 1); BAR();
    // p3 (d0, A1,B0) — drain d1's stages BEFORE the end barrier
    if (s2) STGB(0, 1, t2);
    MID(); MM(1, 0);
    if (s2) { WAITV4; } else { WAITV0; }
    BAR();
    // p4 (d1, A0,B0)
    RDA(1, 0); RDB(1, 0);
    if (s2) STGA(0, 1, t2);
    MID(); MM(0, 0); BAR();
    // p5 (d1, A0,B1)
    RDB(1, 1);
    if (s2) STGB(0, 0, t2);
    MID(); MM(0, 1); BAR();
    // p6 (d1, A1,B1)
    RDA(1, 1);
    if (s3) STGA(1, 0, t3);
    MID(); MM(1, 1); BAR();
    // p7 (d1, A1,B0) — drain next d0's stages BEFORE the end barrier
    if (s3) STGB(1, 1, t3);
    MID(); MM(1, 0);
    if (s3) { WAITV4; }
    BAR();
  }
#undef STGA
#undef STGB
#undef RDA
#undef RDB
#undef MM
#undef MID
  SCHED0();

  if (SMAX) {
    // P = exp(alpha*s) bf16 + per-(row, col-block) partial sums -> smx
    float rs[8][4];
#pragma unroll
    for (int f = 0; f < 8; ++f) {
      const int row0 = bm + wm + f * 32 + lh * 4;
#pragma unroll
      for (int r = 0; r < 4; ++r) rs[f][r] = 0.f;
#pragma unroll
      for (int g = 0; g < 4; ++g) {
        const int col = bn + wn + g * 64 + lr;
#pragma unroll
        for (int r = 0; r < 4; ++r) {
          const float e = __expf(acc[f][g][r] * alpha);
          rs[f][r] += e;
          Cb[(size_t)(row0 + r) * ldc + col] = f2bf(e);
        }
      }
#pragma unroll
      for (int r = 0; r < 4; ++r) {
        float v = rs[f][r];
        v += __shfl_xor(v, 1, 64);
        v += __shfl_xor(v, 2, 64);
        v += __shfl_xor(v, 4, 64);
        v += __shfl_xor(v, 8, 64);
        rs[f][r] = v;
      }
    }
    // cross-wave (over wn) reduction: compile-time-predicated LDS writes
#pragma unroll
    for (int f = 0; f < 8; ++f)
#pragma unroll
      for (int r = 0; r < 4; ++r)
        if (lr == ((f << 1) | (r >> 1)))
          ps[wid & 3][wm + f * 32 + lh * 4 + r] = rs[f][r];
    __syncthreads();
    if (tid < 256) {
      const float tot = ps[0][tid] + ps[1][tid] + ps[2][tid] + ps[3][tid];
      smx[((size_t)(bz * 16 + bx) << 12) + bm + tid] = tot;
    }
  } else {
#pragma unroll
    for (int f = 0; f < 8; ++f) {
      const int row0 = bm + wm + f * 32 + lh * 4;
#pragma unroll
      for (int g = 0; g < 4; ++g) {
        const int col = bn + wn + g * 64 + lr;
#pragma unroll
        for (int r = 0; r < 4; ++r)
          Cb[(size_t)(row0 + r) * ldc + col] = f2bf(acc[f][g][r] * alpha + bias_v[g]);
      }
    }
  }
}

// ---------------- old 128x128 GEMM (kept for V-proj and out-proj) ----------------
#define GBM 128
#define GBN 128
#define GBK 64

template <int BIAS_MODE, int OUT_MODE>
__global__ __launch_bounds__(256) void gemm_abT(
    const u16* __restrict__ Ag, int lda, long sA,
    const u16* __restrict__ Bg, int ldb, long sB,
    void* __restrict__ Cg, int ldc, long sC,
    const float* __restrict__ bias, float alpha,
    const float* __restrict__ xres, int K) {
  __shared__ u16 As[GBM * GBK];
  __shared__ u16 Bs[GBN * GBK];
  const int bz = blockIdx.z;
  const u16* A    = Ag + (size_t)bz * sA;
  const u16* Bmat = Bg + (size_t)bz * sB;
  const int bm = blockIdx.y * GBM, bn = blockIdx.x * GBN;
  const int tid = threadIdx.x;
  const int wid = tid >> 6, lane = tid & 63;
  const int wm = (wid >> 1) * 64, wn = (wid & 1) * 64;
  const int lr = lane & 15, lh = lane >> 4;
  const int srow = lane >> 3, scol = (lane & 7) * 8;

  f32x4 acc[4][4];
  const f32x4 zero = {0.f, 0.f, 0.f, 0.f};
#pragma unroll
  for (int i = 0; i < 4; ++i)
#pragma unroll
    for (int j = 0; j < 4; ++j) acc[i][j] = zero;

  for (int k0 = 0; k0 < K; k0 += GBK) {
    __syncthreads();
#pragma unroll
    for (int i = 0; i < 4; ++i) {
      const int chunk = wid * 4 + i;
      const int row   = chunk * 8 + srow;
      g2lds16(A    + (size_t)(bm + row) * lda + (k0 + scol), &As[chunk * 512]);
      g2lds16(Bmat + (size_t)(bn + row) * ldb + (k0 + scol), &Bs[chunk * 512]);
    }
    __syncthreads();
#pragma unroll
    for (int ks = 0; ks < 2; ++ks) {
      bf16x8 a_[4], b_[4];
#pragma unroll
      for (int m = 0; m < 4; ++m)
        a_[m] = *(const bf16x8*)&As[(wm + m * 16 + lr) * GBK + ks * 32 + lh * 8];
#pragma unroll
      for (int n = 0; n < 4; ++n)
        b_[n] = *(const bf16x8*)&Bs[(wn + n * 16 + lr) * GBK + ks * 32 + lh * 8];
#pragma unroll
      for (int m = 0; m < 4; ++m)
#pragma unroll
        for (int n = 0; n < 4; ++n)
          acc[m][n] = __builtin_amdgcn_mfma_f32_16x16x32_bf16(a_[m], b_[n], acc[m][n], 0, 0, 0);
    }
  }

  if (OUT_MODE == 0) {
    u16* Cb = (u16*)Cg + (size_t)bz * sC;
#pragma unroll
    for (int m = 0; m < 4; ++m) {
      const int row0 = bm + wm + m * 16 + lh * 4;
#pragma unroll
      for (int n = 0; n < 4; ++n) {
        const int col = bn + wn + n * 16 + lr;
        float bn_ = (BIAS_MODE == 1) ? bias[col] : 0.f;
#pragma unroll
        for (int r = 0; r < 4; ++r) {
          float bb = (BIAS_MODE == 2) ? bias[row0 + r] : bn_;
          Cb[(size_t)(row0 + r) * ldc + col] = f2bf(acc[m][n][r] * alpha + bb);
        }
      }
    }
  } else {
    float* Ob = (float*)Cg;
#pragma unroll
    for (int m = 0; m < 4; ++m) {
      const int row0 = bm + wm + m * 16 + lh * 4;
#pragma unroll
      for (int n = 0; n < 4; ++n) {
        const int col = bn + wn + n * 16 + lr;
        const int bb = col >> 12, sp = col & (S_ - 1);
#pragma unroll
        for (int r = 0; r < 4; ++r) {
          const int o = row0 + r;
          const size_t idx = ((size_t)bb * C_ + o) * S_ + sp;
          Ob[idx] = acc[m][n][r] * alpha + bias[o] + xres[idx];
        }
      }
    }
  }
}

extern "C" void kernel_launch(void* const* d_in, const int* in_sizes, int n_in,
                              void* d_out, int out_size, void* d_ws, size_t ws_size,
                              hipStream_t stream) {
  const float* x     = (const float*)d_in[0];
  const float* gamma = (const float*)d_in[1];
  const float* beta  = (const float*)d_in[2];
  const float* wq = (const float*)d_in[3];
  const float* bq = (const float*)d_in[4];
  const float* wk = (const float*)d_in[5];
  const float* bk = (const float*)d_in[6];
  const float* wv = (const float*)d_in[7];
  const float* bv = (const float*)d_in[8];
  const float* wo = (const float*)d_in[9];
  const float* bo = (const float*)d_in[10];
  float* out = (float*)d_out;

  // ws: stats 1KB | weights bf16 4x512KB | bqk 4KB | ht 16MB | qkt 32MB | vv 16MB
  //     | sc 128MB | partials 1MB | Lr 64KB
  char* ws = (char*)d_ws;
  float* stats = (float*)ws;
  u16* wqb = (u16*)(ws + 1024);
  u16* wkb = wqb + 262144;   // contiguous after wqb -> [wq;wk] is one 1024x512 matrix
  u16* wvb = wkb + 262144;
  u16* wob = wvb + 262144;
  float* bqk = (float*)(wob + 262144);
  u16* ht  = (u16*)((char*)bqk + 4096);  // [B*S, C]
  u16* qkt = ht + 8388608;               // [B*S, 1024] (q|k); later PV psum halves
  u16* vv  = qkt + 16777216;             // [C, B*S]; later normalized hattnT
  u16* sc  = vv + 8388608;               // [B, S, S] exp(scores)
  float* partials = (float*)(sc + 67108864);  // [B][16][4096]
  float* Lr = partials + 262144;              // [B][4096]

  f32_to_bf16<<<1024, 256, 0, stream>>>(wq, wqb, 262144);
  f32_to_bf16<<<1024, 256, 0, stream>>>(wk, wkb, 262144);
  f32_to_bf16<<<1024, 256, 0, stream>>>(wv, wvb, 262144);
  f32_to_bf16<<<1024, 256, 0, stream>>>(wo, wob, 262144);
  concat_bias<<<4, 256, 0, stream>>>(bq, bk, bqk);

  gn_stats<<<128, 256, 0, stream>>>(x, stats);
  gn_apply_t<<<dim3(128, 16, 4), dim3(32, 8), 0, stream>>>(x, gamma, beta, stats, ht);

  // fused Q|K projection: qkt[bs, 0:512]=Q, [512:1024]=K   (256 blocks)
  gemm8p<1, 0, 0><<<dim3(4, 64, 1), 512, 0, stream>>>(ht, 512, 0, wqb, 512, 0,
                                                      qkt, 1024, 0, bqk, 1.f, 512, nullptr);
  // V[c, b*S+s]: bias per m (=c)                            (512 blocks)
  gemm_abT<2, 0><<<dim3(128, 4, 1), 256, 0, stream>>>(wvb, 512, 0, ht, 512, 0,
                                                      vv, 16384, 0, bv, 1.f, nullptr, 512);
  // P[b,i,j] = exp(scale * Q.K) + row-sum partials          (1024 blocks)
  gemm8p<0, 0, 1><<<dim3(16, 16, 4), 512, 0, stream>>>(qkt, 1024, 4194304, qkt + 512, 1024, 4194304,
                                                       sc, 4096, 16777216, nullptr,
                                                       0.04419417382415922f, 512, partials);
  reduce_l<<<64, 256, 0, stream>>>(partials, Lr);
  // PV split-K=2 on unnormalized P: psums in qkt halves     (256 blocks)
  gemm8p<0, 1, 0><<<dim3(2, 16, 8), 512, 0, stream>>>(sc, 4096, 0, vv, 16384, 0,
                                                      qkt, 512, 0, nullptr, 1.f, 2048, nullptr);
  // combine psums + apply 1/l row scale -> normalized hattnT in vv
  add_scale_bf16<<<4096, 256, 0, stream>>>(qkt, qkt + 8388608, Lr, vv);
  // out[b,o,s] = Wo@hattn + bo + x  (fp32 + residual)       (512 blocks)
  gemm_abT<2, 1><<<dim3(128, 4, 1), 256, 0, stream>>>(wob, 512, 0, vv, 512, 0,
                                                      out, 0, 0, bo, 1.f, x, 512);
}